// Round 1
// baseline (1016.735 us; speedup 1.0000x reference)
//
#include <hip/hip_runtime.h>
#include <math.h>

#define D 256
#define HEADS 8
#define DH 32
#define INTER 50
#define INTRA 20
#define BSZ 256
#define CANDN 2048
#define ROWS (BSZ*INTER)   // 12800
#define NITEMS 200000

typedef unsigned short ushort_t;
typedef __attribute__((ext_vector_type(8))) short bf16x8;
typedef __attribute__((ext_vector_type(4))) float f32x4;

__device__ __forceinline__ unsigned short f2b(float f) {
    union { float f; unsigned u; } v; v.f = f;
    unsigned r = v.u + 0x7fffu + ((v.u >> 16) & 1u);
    return (unsigned short)(r >> 16);
}
__device__ __forceinline__ float b2f(unsigned short h) {
    union { unsigned u; float f; } v; v.u = ((unsigned)h) << 16;
    return v.f;
}
__device__ __forceinline__ void gl_lds16(const void* g, void* l) {
    __builtin_amdgcn_global_load_lds(
        (const __attribute__((address_space(1))) unsigned int*)g,
        (__attribute__((address_space(3))) unsigned int*)l, 16, 0, 0);
}
// XOR swizzle within a 512B row (K=256 bf16): spreads same-column reads
// across 8 distinct 16B slots -> 2 lanes/bank (free, m136).
__device__ __forceinline__ int swz(int row, int kb) {
    return row*512 + (kb ^ ((row & 7) << 4));
}

// ============ prep: item fp32->bf16 table + 6 weight transposes + bcat ====
__device__ __forceinline__ void wtr_body(const float* __restrict__ W, int K, int N,
    unsigned short* __restrict__ WT, int bx, int by, float (*tile)[33], int t)
{
    int n0 = bx*32, k0 = by*32;
    int tx = t & 31, ty = t >> 5;
    for (int i = ty; i < 32; i += 8)
        tile[i][tx] = W[(size_t)(k0+i)*N + n0 + tx];
    __syncthreads();
    for (int i = ty; i < 32; i += 8)
        WT[(size_t)(n0+i)*K + k0 + tx] = f2b(tile[tx][i]);
}

__global__ __launch_bounds__(256) void prep_k(
    const float* __restrict__ item_emb, unsigned short* __restrict__ item_b, int itemBlocks,
    const float* __restrict__ Wq, const float* __restrict__ Wk,
    const float* __restrict__ Wv, const float* __restrict__ Wo,
    const float* __restrict__ W1, const float* __restrict__ W2,
    unsigned short* __restrict__ WqkvT, unsigned short* __restrict__ WoT,
    unsigned short* __restrict__ W1T, unsigned short* __restrict__ W2T,
    const float* __restrict__ bq, const float* __restrict__ bk,
    const float* __restrict__ bv, float* __restrict__ bqkv)
{
    __shared__ float tile[32][33];
    int blk = blockIdx.x, t = threadIdx.x;
    if (blk < itemBlocks) {
        int i = blk*256 + t;
        float4 v = ((const float4*)item_emb)[i];
        ushort4 h; h.x=f2b(v.x); h.y=f2b(v.y); h.z=f2b(v.z); h.w=f2b(v.w);
        ((ushort4*)item_b)[i] = h;
        return;
    }
    blk -= itemBlocks;
    if (blk < 64)       wtr_body(Wq, 256, 256,  WqkvT,            blk & 7,  blk >> 3, tile, t);
    else if (blk < 128) wtr_body(Wk, 256, 256,  WqkvT + 256*256, (blk-64) & 7,  (blk-64) >> 3, tile, t);
    else if (blk < 192) wtr_body(Wv, 256, 256,  WqkvT + 512*256, (blk-128) & 7, (blk-128) >> 3, tile, t);
    else if (blk < 256) wtr_body(Wo, 256, 256,  WoT,             (blk-192) & 7, (blk-192) >> 3, tile, t);
    else if (blk < 512) { int id = blk-256; wtr_body(W1, 256, 1024, W1T, id & 31, id >> 5, tile, t); }
    else if (blk < 768) { int id = blk-512; wtr_body(W2, 1024, 256, W2T, id & 7,  id >> 3, tile, t); }
    else { bqkv[t] = bq[t]; bqkv[256+t] = bk[t]; bqkv[512+t] = bv[t]; }
}

// ============ intra-session attention via MFMA ============================
#define XST 264
__global__ __launch_bounds__(256) void intra_k(
    const float* __restrict__ item_emb, const unsigned short* __restrict__ item_b,
    const int* __restrict__ sess,
    float* __restrict__ S, float* __restrict__ u_short)
{
    __shared__ __align__(16) unsigned short xb[4][INTRA][XST];
    __shared__ __align__(16) unsigned short zrow[XST];
    __shared__ float sc[4][20][21];
    __shared__ float wsum[4][20];
    __shared__ int ids[4][INTRA];
    int t = threadIdx.x, w = t >> 6, lane = t & 63;
    int s = blockIdx.x*4 + w;
    if (lane < INTRA) ids[w][lane] = sess[s*INTRA + lane];
    if (t < 132) ((unsigned int*)zrow)[t] = 0u;
    __syncthreads();
    int col = lane*4;
    for (int r = 0; r < INTRA; ++r) {
        int id = ids[w][r];
        ushort4 h;
        if (id == 0) { h.x=h.y=h.z=h.w=0; }
        else if (item_b) {
            h = *(const ushort4*)(item_b + (size_t)id*D + col);
        } else {
            float4 v4 = *(const float4*)(item_emb + (size_t)id*D + col);
            h.x=f2b(v4.x); h.y=f2b(v4.y); h.z=f2b(v4.z); h.w=f2b(v4.w);
        }
        *(ushort4*)&xb[w][r][col] = h;
    }
    __syncthreads();
    int ml = lane & 15, q8 = (lane >> 4) * 8;
    int r1 = 16 + ml;
    f32x4 acc[2][2] = {};
    for (int k0 = 0; k0 < D; k0 += 32) {
        bf16x8 fr0 = *(const bf16x8*)&xb[w][ml][k0 + q8];
        bf16x8 fr1 = (r1 < INTRA) ? *(const bf16x8*)&xb[w][r1][k0 + q8]
                                  : *(const bf16x8*)&zrow[q8];
        acc[0][0] = __builtin_amdgcn_mfma_f32_16x16x32_bf16(fr0, fr0, acc[0][0], 0,0,0);
        acc[0][1] = __builtin_amdgcn_mfma_f32_16x16x32_bf16(fr0, fr1, acc[0][1], 0,0,0);
        acc[1][0] = __builtin_amdgcn_mfma_f32_16x16x32_bf16(fr1, fr0, acc[1][0], 0,0,0);
        acc[1][1] = __builtin_amdgcn_mfma_f32_16x16x32_bf16(fr1, fr1, acc[1][1], 0,0,0);
    }
    int rb = (lane >> 4) * 4;
    #pragma unroll
    for (int mt = 0; mt < 2; ++mt)
        #pragma unroll
        for (int nt = 0; nt < 2; ++nt)
            #pragma unroll
            for (int i = 0; i < 4; ++i) {
                int row = mt*16 + rb + i, cc = nt*16 + ml;
                if (row < INTRA && cc < INTRA) sc[w][row][cc] = acc[mt][nt][i];
            }
    __syncthreads();
    if (lane < INTRA) {
        float vrow[INTRA]; float mx = -1e30f;
        #pragma unroll
        for (int k = 0; k < INTRA; ++k) {
            float v_ = (ids[w][k] != 0) ? sc[w][lane][k]*(1.0f/16.0f) : -1e9f;
            vrow[k] = v_; mx = fmaxf(mx, v_);
        }
        float ssum = 0.f;
        #pragma unroll
        for (int k = 0; k < INTRA; ++k) { float e_ = expf(vrow[k]-mx); vrow[k]=e_; ssum+=e_; }
        float inv = 1.f/ssum;
        #pragma unroll
        for (int k = 0; k < INTRA; ++k) sc[w][lane][k] = vrow[k]*inv;
    }
    __syncthreads();
    if (lane < INTRA) {
        float s_ = 0.f;
        #pragma unroll
        for (int q = 0; q < INTRA; ++q) s_ += sc[w][q][lane];
        wsum[w][lane] = s_;
    }
    __syncthreads();
    float4 v = {0.f,0.f,0.f,0.f};
    #pragma unroll
    for (int k = 0; k < INTRA; ++k) {
        float ws_ = wsum[w][k];
        ushort4 h = *(const ushort4*)&xb[w][k][col];
        v.x += ws_*b2f(h.x); v.y += ws_*b2f(h.y);
        v.z += ws_*b2f(h.z); v.w += ws_*b2f(h.w);
    }
    int b = s / INTER, srow = s % INTER;
    if (srow == INTER-1) *(float4*)(u_short + (size_t)b*D + col) = v;
    const float kc = -9.210340371976184f / 256.0f;
    float div0 = expf((float)col * kc);
    float div2 = expf((float)(col+2) * kc);
    float4 o;
    o.x = v.x + sinf((float)srow * div0);
    o.y = v.y + cosf((float)srow * div0);
    o.z = v.z + sinf((float)srow * div2);
    o.w = v.w + cosf((float)srow * div2);
    *(float4*)(S + (size_t)s*D + col) = o;
}

// ============ fused LN + fully-LDS-resident GEMM (K=256 only) =============
// A-panel (128x256 bf16, 64KB) + B-panel (128x256 bf16, 64KB) both resident;
// one barrier, then a barrier-free K-loop of 128 MFMAs per wave.
// flags: bit0 = fp32 accumulate into Cf, bit1 = relu, bit2 = LN on fp32 A.
#define TM 128
#define TN 128
__global__ __launch_bounds__(256) void gemmf_k(
    const float* __restrict__ Af, const unsigned short* __restrict__ Ab, int lda,
    const unsigned short* __restrict__ BT,
    const float* __restrict__ lng, const float* __restrict__ lnb,
    const float* __restrict__ bias,
    float* __restrict__ Cf, unsigned short* __restrict__ Cb, int ldc, int flags)
{
    __shared__ __align__(16) unsigned short As[TM*256];
    __shared__ __align__(16) unsigned short Bs[TN*256];
    int tid = threadIdx.x, lane = tid & 63, w = tid >> 6;
    int tile_m = blockIdx.y*TM, tile_n = blockIdx.x*TN;
    // ---- stage B (always bf16, reg->swizzled LDS) ----
    #pragma unroll
    for (int i = 0; i < 16; ++i) {
        int c = tid + 256*i;
        int row = c >> 5, kb = (c & 31)*16;
        bf16x8 v = *(const bf16x8*)((const char*)BT + (size_t)(tile_n + row)*512 + kb);
        *(bf16x8*)((char*)Bs + swz(row, kb)) = v;
    }
    // ---- stage A ----
    if (flags & 4) {
        // fp32 rows of S -> LayerNorm(ddof=1) -> bf16, wave w owns rows [32w,32w+32)
        int col = lane*4;
        float4 g4 = *(const float4*)(lng + col);
        float4 b4 = *(const float4*)(lnb + col);
        #pragma unroll
        for (int rr = 0; rr < 32; rr += 8) {
            float4 x[8];
            #pragma unroll
            for (int j = 0; j < 8; ++j)
                x[j] = *(const float4*)(Af + (size_t)(tile_m + w*32 + rr + j)*lda + col);
            #pragma unroll
            for (int j = 0; j < 8; ++j) {
                int row = w*32 + rr + j;
                float s = x[j].x + x[j].y + x[j].z + x[j].w;
                #pragma unroll
                for (int o = 32; o > 0; o >>= 1) s += __shfl_xor(s, o, 64);
                float mean = s * (1.f/256.f);
                float dx = x[j].x - mean, dy = x[j].y - mean;
                float dz = x[j].z - mean, dw = x[j].w - mean;
                float q = dx*dx + dy*dy + dz*dz + dw*dw;
                #pragma unroll
                for (int o = 32; o > 0; o >>= 1) q += __shfl_xor(q, o, 64);
                float inv = 1.f/(sqrtf(q*(1.f/255.f)) + 1e-6f);
                ushort4 h;
                h.x = f2b(g4.x*dx*inv + b4.x);
                h.y = f2b(g4.y*dy*inv + b4.y);
                h.z = f2b(g4.z*dz*inv + b4.z);
                h.w = f2b(g4.w*dw*inv + b4.w);
                *(ushort4*)((char*)As + swz(row, lane*8)) = h;
            }
        }
    } else {
        #pragma unroll
        for (int i = 0; i < 16; ++i) {
            int c = tid + 256*i;
            int row = c >> 5, kb = (c & 31)*16;
            bf16x8 v = *(const bf16x8*)((const char*)Ab + (size_t)(tile_m + row)*lda*2 + kb);
            *(bf16x8*)((char*)As + swz(row, kb)) = v;
        }
    }
    __syncthreads();
    // ---- barrier-free K loop ----
    int ml = lane & 15, q8 = (lane >> 4)*8;
    int wrow = (w >> 1)*64, wcol = (w & 1)*64;
    f32x4 acc[4][4] = {};
    #pragma unroll
    for (int k0 = 0; k0 < 256; k0 += 32) {
        bf16x8 af[4], bfr[4];
        #pragma unroll
        for (int mt = 0; mt < 4; ++mt)
            af[mt] = *(const bf16x8*)((char*)As + swz(wrow + mt*16 + ml, (k0 + q8)*2));
        #pragma unroll
        for (int nt = 0; nt < 4; ++nt)
            bfr[nt] = *(const bf16x8*)((char*)Bs + swz(wcol + nt*16 + ml, (k0 + q8)*2));
        #pragma unroll
        for (int mt = 0; mt < 4; ++mt)
            #pragma unroll
            for (int nt = 0; nt < 4; ++nt)
                acc[mt][nt] = __builtin_amdgcn_mfma_f32_16x16x32_bf16(
                    af[mt], bfr[nt], acc[mt][nt], 0, 0, 0);
    }
    // ---- epilogue ----
    int col_l = lane & 15, rbase = (lane >> 4)*4;
    #pragma unroll
    for (int mt = 0; mt < 4; ++mt) {
        #pragma unroll
        for (int nt = 0; nt < 4; ++nt) {
            int col = tile_n + wcol + nt*16 + col_l;
            float bs = bias ? bias[col] : 0.f;
            #pragma unroll
            for (int i = 0; i < 4; ++i) {
                size_t row = tile_m + wrow + mt*16 + rbase + i;
                float v_ = acc[mt][nt][i] + bs;
                if (flags & 2) v_ = fmaxf(v_, 0.f);
                if (flags & 1) Cf[row*ldc + col] += v_;
                else           Cb[row*ldc + col] = f2b(v_);
            }
        }
    }
}

// ============ bf16 MFMA GEMM (kept for K=1024 W2 pass) ====================
__global__ __launch_bounds__(256) void mgemm_k(
    const unsigned short* __restrict__ A, int lda,
    const unsigned short* __restrict__ BT,
    const float* __restrict__ bias,
    float* __restrict__ Cf, unsigned short* __restrict__ Cb,
    int ldc, int K, int flags)
{
    __shared__ __align__(16) unsigned short As[2][TM*32];
    __shared__ __align__(16) unsigned short Bs[2][TN*32];
    int tid = threadIdx.x;
    int lane = tid & 63, w = tid >> 6;
    int wrow = (w >> 1) * 64, wcol = (w & 1) * 64;
    int tile_m = blockIdx.y * TM, tile_n = blockIdx.x * TN;
    f32x4 acc[4][4] = {};
    const int r_in_chunk = lane >> 2;
    const int e_in_row = (lane & 3) * 8;
    const int qoff = (lane >> 4) * 8;
    const int ml = lane & 15;
    for (int k0 = 0; k0 < K; k0 += 64) {
        #pragma unroll
        for (int h = 0; h < 2; ++h) {
            #pragma unroll
            for (int i = 0; i < 2; ++i) {
                int c = w*2 + i;
                int row = c*16 + r_in_chunk;
                gl_lds16(A + (size_t)(tile_m + row)*lda + k0 + h*32 + e_in_row,
                         (char*)As[h] + c*1024 + lane*16);
            }
            #pragma unroll
            for (int i = 0; i < 2; ++i) {
                int c = w*2 + i;
                int row = c*16 + r_in_chunk;
                gl_lds16(BT + (size_t)(tile_n + row)*K + k0 + h*32 + e_in_row,
                         (char*)Bs[h] + c*1024 + lane*16);
            }
        }
        __syncthreads();
        #pragma unroll
        for (int h = 0; h < 2; ++h) {
            bf16x8 af[4], bfr[4];
            #pragma unroll
            for (int mt = 0; mt < 4; ++mt)
                af[mt] = *(const bf16x8*)(As[h] + (wrow + mt*16 + ml)*32 + qoff);
            #pragma unroll
            for (int nt = 0; nt < 4; ++nt)
                bfr[nt] = *(const bf16x8*)(Bs[h] + (wcol + nt*16 + ml)*32 + qoff);
            #pragma unroll
            for (int mt = 0; mt < 4; ++mt)
                #pragma unroll
                for (int nt = 0; nt < 4; ++nt)
                    acc[mt][nt] = __builtin_amdgcn_mfma_f32_16x16x32_bf16(
                        af[mt], bfr[nt], acc[mt][nt], 0, 0, 0);
        }
        __syncthreads();
    }
    int col_l = lane & 15, rbase = (lane >> 4) * 4;
    #pragma unroll
    for (int mt = 0; mt < 4; ++mt) {
        #pragma unroll
        for (int nt = 0; nt < 4; ++nt) {
            int col = tile_n + wcol + nt*16 + col_l;
            float bs = bias ? bias[col] : 0.f;
            #pragma unroll
            for (int i = 0; i < 4; ++i) {
                size_t row = tile_m + wrow + mt*16 + rbase + i;
                float v_ = acc[mt][nt][i] + bs;
                if (flags & 2) v_ = fmaxf(v_, 0.f);
                if (flags & 1) Cf[row*ldc + col] += v_;
                else           Cb[row*ldc + col] = f2b(v_);
            }
        }
    }
}

// ============ inter-session MHA via MFMA: block per (b,h) =================
#define AST 40
#define PST 72
__global__ __launch_bounds__(256) void att_k(
    const unsigned short* __restrict__ QKV, const int* __restrict__ sess,
    unsigned short* __restrict__ O)
{
    __shared__ __align__(16) unsigned short qs[64][AST];
    __shared__ __align__(16) unsigned short ks[64][AST];
    __shared__ __align__(16) unsigned short vst[32][PST];
    __shared__ __align__(16) unsigned short pb[64][PST];
    __shared__ float p[50][52];
    __shared__ float msk[52];
    int b = blockIdx.x >> 3, h = blockIdx.x & 7;
    int t = threadIdx.x, w = t >> 6, lane = t & 63;
    for (int u = t; u < 400; u += 256) {
        int arr = u / 200, rem = u % 200, row = rem >> 2, part = rem & 3;
        const unsigned short* src = QKV + ((size_t)(b*INTER+row))*768 + arr*256 + h*32 + part*8;
        ushort4 a = *(const ushort4*)src, c = *(const ushort4*)(src+4);
        unsigned short* dst = (arr ? ks[row] : qs[row]) + part*8;
        *(ushort4*)dst = a; *(ushort4*)(dst+4) = c;
    }
    for (int u = t; u < INTER*32; u += 256) {
        int row = u >> 5, e = u & 31;
        vst[e][row] = QKV[((size_t)(b*INTER+row))*768 + 512 + h*32 + e];
    }
    for (int u = t; u < 32*14; u += 256) {
        int e = u / 14, k = 50 + (u % 14);
        vst[e][k] = 0;
    }
    for (int u = t; u < 64*14; u += 256) {
        int r = u / 14, k = 50 + (u % 14);
        pb[r][k] = 0;
    }
    if (t < INTER) msk[t] = (sess[(b*INTER + t)*INTRA] != 0) ? 1.f : 0.f;
    __syncthreads();
    int ml = lane & 15, q8 = (lane >> 4) * 8, rb = (lane >> 4) * 4;
    {
        bf16x8 afq = *(const bf16x8*)&qs[w*16 + ml][q8];
        #pragma unroll
        for (int nt = 0; nt < 4; ++nt) {
            bf16x8 bfk = *(const bf16x8*)&ks[nt*16 + ml][q8];
            f32x4 a0 = {};
            a0 = __builtin_amdgcn_mfma_f32_16x16x32_bf16(afq, bfk, a0, 0, 0, 0);
            #pragma unroll
            for (int i = 0; i < 4; ++i) {
                int row = w*16 + rb + i, cc = nt*16 + ml;
                if (row < INTER && cc < INTER)
                    p[row][cc] = (msk[cc] != 0.f) ? a0[i]*0.17677669529663687f : -1e9f;
            }
        }
    }
    __syncthreads();
    {
        int r0 = w*13, r1 = r0+13; if (r1 > INTER) r1 = INTER;
        for (int r = r0; r < r1; ++r) {
            float v = (lane < INTER) ? p[r][lane] : -1e30f;
            float m = v;
            #pragma unroll
            for (int off = 32; off > 0; off >>= 1) m = fmaxf(m, __shfl_xor(m, off, 64));
            float e_ = (lane < INTER) ? expf(v - m) : 0.f;
            float ssum = e_;
            #pragma unroll
            for (int off = 32; off > 0; off >>= 1) ssum += __shfl_xor(ssum, off, 64);
            if (lane < INTER) pb[r][lane] = f2b(e_ / ssum);
        }
    }
    __syncthreads();
    f32x4 acco[2] = {};
    #pragma unroll
    for (int kt = 0; kt < 2; ++kt) {
        bf16x8 ap = *(const bf16x8*)&pb[w*16 + ml][kt*32 + q8];
        #pragma unroll
        for (int nt = 0; nt < 2; ++nt) {
            bf16x8 bv = *(const bf16x8*)&vst[nt*16 + ml][kt*32 + q8];
            acco[nt] = __builtin_amdgcn_mfma_f32_16x16x32_bf16(ap, bv, acco[nt], 0, 0, 0);
        }
    }
    #pragma unroll
    for (int nt = 0; nt < 2; ++nt)
        #pragma unroll
        for (int i = 0; i < 4; ++i) {
            int row = w*16 + rb + i, cc = nt*16 + ml;
            if (row < INTER)
                O[((size_t)(b*INTER+row))*D + h*DH + cc] = f2b(acco[nt][i]);
        }
}

// ============ fused tail: final LN + u_long + gate ========================
__global__ __launch_bounds__(256) void tail_k(
    const float* __restrict__ S,
    const float* __restrict__ fn_g, const float* __restrict__ fn_b,
    const float* __restrict__ user_emb, const int* __restrict__ us,
    const float* __restrict__ time_emb, const int* __restrict__ tdlt,
    const float* __restrict__ u_short,
    const float* __restrict__ Wl, const float* __restrict__ Ws,
    const float* __restrict__ Wt, const float* __restrict__ gb,
    float* __restrict__ U)
{
    __shared__ float part[4][D];
    __shared__ float ul[D], ush[D], te[D];
    int b = blockIdx.x, t = threadIdx.x, w = t >> 6, lane = t & 63;
    int col = lane*4;
    float4 g4 = *(const float4*)(fn_g + col);
    float4 b4 = *(const float4*)(fn_b + col);
    float4 acc4 = {0.f,0.f,0.f,0.f};
    for (int l = w; l < INTER; l += 4) {
        float4 x = *(const float4*)(S + (size_t)(b*INTER + l)*D + col);
        float s = x.x + x.y + x.z + x.w;
        #pragma unroll
        for (int o = 32; o > 0; o >>= 1) s += __shfl_xor(s, o, 64);
        float mean = s * (1.f/256.f);
        float dx = x.x - mean, dy = x.y - mean, dz = x.z - mean, dw = x.w - mean;
        float q = dx*dx + dy*dy + dz*dz + dw*dw;
        #pragma unroll
        for (int o = 32; o > 0; o >>= 1) q += __shfl_xor(q, o, 64);
        float inv = 1.f/(sqrtf(q*(1.f/255.f)) + 1e-6f);
        acc4.x += g4.x*dx*inv + b4.x;
        acc4.y += g4.y*dy*inv + b4.y;
        acc4.z += g4.z*dz*inv + b4.z;
        acc4.w += g4.w*dw*inv + b4.w;
    }
    *(float4*)&part[w][col] = acc4;
    __syncthreads();
    int id = us[b];
    float ue = (id == 0) ? 0.f : user_emb[(size_t)id*D + t];
    float ulv = part[0][t] + part[1][t] + part[2][t] + part[3][t] + ue;
    ul[t]  = ulv;
    float ushv = u_short[b*D + t];
    ush[t] = ushv;
    te[t]  = time_emb[(size_t)tdlt[b]*D + t];
    __syncthreads();
    float a = gb[t];
    for (int k = 0; k < D; ++k)
        a += ul[k]*Wl[k*D + t] + ush[k]*Ws[k*D + t] + te[k]*Wt[k*D + t];
    float tg = 1.f/(1.f + expf(-a));
    U[b*D + t] = tg*ushv + (1.f - tg)*ulv;
}

// ============ candidate scoring ===========================================
__global__ __launch_bounds__(256) void out_k(
    const float* __restrict__ item_emb, const unsigned short* __restrict__ item_b,
    const int* __restrict__ pred,
    const float* __restrict__ U, float* __restrict__ out)
{
    int b = blockIdx.x >> 6;
    int cbase = (blockIdx.x & 63) * 32;
    int t = threadIdx.x, w = t >> 6, lane = t & 63;
    int hl = lane & 31, half = lane >> 5;
    float4 u0 = *(const float4*)(U + (size_t)b*D + hl*8);
    float4 u1 = *(const float4*)(U + (size_t)b*D + hl*8 + 4);
    for (int it = 0; it < 4; ++it) {
        int c = cbase + it*8 + w*2 + half;
        int id = pred[b*CANDN + c];
        float p = 0.f;
        if (id) {
            if (item_b) {
                const unsigned short* row = item_b + (size_t)id*D + hl*8;
                ushort4 a = *(const ushort4*)row;
                ushort4 d = *(const ushort4*)(row+4);
                p = b2f(a.x)*u0.x + b2f(a.y)*u0.y + b2f(a.z)*u0.z + b2f(a.w)*u0.w
                  + b2f(d.x)*u1.x + b2f(d.y)*u1.y + b2f(d.z)*u1.z + b2f(d.w)*u1.w;
            } else {
                const float* row = item_emb + (size_t)id*D + hl*8;
                float4 a = *(const float4*)row;
                float4 d = *(const float4*)(row+4);
                p = a.x*u0.x + a.y*u0.y + a.z*u0.z + a.w*u0.w
                  + d.x*u1.x + d.y*u1.y + d.z*u1.z + d.w*u1.w;
            }
        }
        #pragma unroll
        for (int off = 16; off > 0; off >>= 1) p += __shfl_xor(p, off, 64);
        if (hl == 0) out[b*CANDN + c] = p;
    }
}

// ---------------------------------------------------------------------------
extern "C" void kernel_launch(void* const* d_in, const int* in_sizes, int n_in,
                              void* d_out, int out_size, void* d_ws, size_t ws_size,
                              hipStream_t stream)
{
    const float* item_emb = (const float*)d_in[0];
    const float* user_emb = (const float*)d_in[1];
    const float* time_emb = (const float*)d_in[2];
    const float* Wq = (const float*)d_in[3];  const float* bq = (const float*)d_in[4];
    const float* Wk = (const float*)d_in[5];  const float* bk = (const float*)d_in[6];
    const float* Wv = (const float*)d_in[7];  const float* bv = (const float*)d_in[8];
    const float* Wo = (const float*)d_in[9];  const float* bo = (const float*)d_in[10];
    const float* ln1_g = (const float*)d_in[11]; const float* ln1_b = (const float*)d_in[12];
    const float* W1 = (const float*)d_in[13]; const float* b1 = (const float*)d_in[14];
    const float* W2 = (const float*)d_in[15]; const float* b2 = (const float*)d_in[16];
    const float* ln2_g = (const float*)d_in[17]; const float* ln2_b = (const float*)d_in[18];
    const float* fn_g = (const float*)d_in[19]; const float* fn_b = (const float*)d_in[20];
    const float* gWl = (const float*)d_in[21]; const float* gWs = (const float*)d_in[22];
    const float* gWt = (const float*)d_in[23]; const float* gbias = (const float*)d_in[24];
    const int* us   = (const int*)d_in[25];
    const int* sess = (const int*)d_in[26];
    const int* tdlt = (const int*)d_in[27];
    const int* pred = (const int*)d_in[28];
    float* out = (float*)d_out;

    char* base = (char*)d_ws;
    size_t off = 0;
    float* S = (float*)(base+off);              off += (size_t)ROWS*D*4;
    unsigned short* Ybf = (unsigned short*)(base+off); off += (size_t)ROWS*D*2;
    unsigned short* QKVb = (unsigned short*)(base+off);
    unsigned short* Hb = QKVb;
    off += (size_t)ROWS*1024*2;
    unsigned short* WqkvT = (unsigned short*)(base+off); off += (size_t)768*256*2;
    unsigned short* WoT   = (unsigned short*)(base+off); off += (size_t)256*256*2;
    unsigned short* W1T   = (unsigned short*)(base+off); off += (size_t)1024*256*2;
    unsigned short* W2T   = (unsigned short*)(base+off); off += (size_t)256*1024*2;
    float* bqkv = (float*)(base+off);            off += 768*4;
    float* u_short = (float*)(base+off);         off += BSZ*D*4;
    float* u_long  = (float*)(base+off);         off += BSZ*D*4;
    float* Ufin    = (float*)(base+off);         off += BSZ*D*4;
    (void)u_long;
    unsigned short* item_b = (unsigned short*)(base+off);
    size_t item_b_bytes = (size_t)NITEMS*D*2;
    bool use_b16 = (off + item_b_bytes) <= ws_size;
    if (!use_b16) item_b = nullptr;

    // 0. prep: item table + weight transposes + bias concat (one kernel)
    int itemBlocks = use_b16 ? (NITEMS*D/4)/256 : 0;
    prep_k<<<itemBlocks + 769, 256, 0, stream>>>(
        item_emb, item_b, itemBlocks,
        Wq, Wk, Wv, Wo, W1, W2,
        WqkvT, WoT, W1T, W2T,
        bq, bk, bv, bqkv);

    // 1. intra-session attention (MFMA)
    intra_k<<<ROWS/4, 256, 0, stream>>>(item_emb, item_b, sess, S, u_short);

    // 2. transformer blocks (LN fused into the K=256 GEMMs)
    for (int blk = 0; blk < 2; ++blk) {
        // QKV = LN1(S) @ Wqkv + b   (bf16 out)
        gemmf_k<<<dim3(6,100), 256, 0, stream>>>(S, nullptr, D, WqkvT,
            ln1_g, ln1_b, bqkv, nullptr, QKVb, 768, 4);
        att_k<<<BSZ*HEADS, 256, 0, stream>>>(QKVb, sess, Ybf);
        // S += att @ Wo + bo        (fp32 accumulate)
        gemmf_k<<<dim3(2,100), 256, 0, stream>>>(nullptr, Ybf, D, WoT,
            nullptr, nullptr, bo, S, nullptr, 256, 1);
        // H = relu(LN2(S) @ W1 + b1) (bf16 out)
        gemmf_k<<<dim3(8,100), 256, 0, stream>>>(S, nullptr, D, W1T,
            ln2_g, ln2_b, b1, nullptr, Hb, 1024, 6);
        // S += H @ W2 + b2          (K=1024, staged GEMM)
        mgemm_k<<<dim3(2,100), 256, 0, stream>>>(Hb, 1024, W2T, b2,
            S, nullptr, 256, 1024, 1);
    }

    // 3. fused tail: final LN + u_long + gate
    tail_k<<<BSZ, 256, 0, stream>>>(S, fn_g, fn_b, user_emb, us,
        time_emb, tdlt, u_short, gWl, gWs, gWt, gbias, Ufin);

    // 4. candidate scores
    out_k<<<(BSZ*CANDN)/32, 256, 0, stream>>>(item_emb, item_b, pred, Ufin, out);
}

// Round 2
// 837.663 us; speedup vs baseline: 1.2138x; 1.2138x over previous
//
#include <hip/hip_runtime.h>
#include <math.h>

#define D 256
#define HEADS 8
#define DH 32
#define INTER 50
#define INTRA 20
#define BSZ 256
#define CANDN 2048
#define ROWS (BSZ*INTER)   // 12800
#define NITEMS 200000

typedef unsigned short ushort_t;
typedef __attribute__((ext_vector_type(8))) short bf16x8;
typedef __attribute__((ext_vector_type(4))) float f32x4;

__device__ __forceinline__ unsigned short f2b(float f) {
    union { float f; unsigned u; } v; v.f = f;
    unsigned r = v.u + 0x7fffu + ((v.u >> 16) & 1u);
    return (unsigned short)(r >> 16);
}
__device__ __forceinline__ float b2f(unsigned short h) {
    union { unsigned u; float f; } v; v.u = ((unsigned)h) << 16;
    return v.f;
}
__device__ __forceinline__ void gl_lds16(const void* g, void* l) {
    __builtin_amdgcn_global_load_lds(
        (const __attribute__((address_space(1))) unsigned int*)g,
        (__attribute__((address_space(3))) unsigned int*)l, 16, 0, 0);
}

// ============ prep: item fp32->bf16 table + 6 weight transposes + bcat ====
__device__ __forceinline__ void wtr_body(const float* __restrict__ W, int K, int N,
    unsigned short* __restrict__ WT, int bx, int by, float (*tile)[33], int t)
{
    int n0 = bx*32, k0 = by*32;
    int tx = t & 31, ty = t >> 5;
    for (int i = ty; i < 32; i += 8)
        tile[i][tx] = W[(size_t)(k0+i)*N + n0 + tx];
    __syncthreads();
    for (int i = ty; i < 32; i += 8)
        WT[(size_t)(n0+i)*K + k0 + tx] = f2b(tile[tx][i]);
}

__global__ __launch_bounds__(256) void prep_k(
    const float* __restrict__ item_emb, unsigned short* __restrict__ item_b, int itemBlocks,
    const float* __restrict__ Wq, const float* __restrict__ Wk,
    const float* __restrict__ Wv, const float* __restrict__ Wo,
    const float* __restrict__ W1, const float* __restrict__ W2,
    unsigned short* __restrict__ WqkvT, unsigned short* __restrict__ WoT,
    unsigned short* __restrict__ W1T, unsigned short* __restrict__ W2T,
    const float* __restrict__ bq, const float* __restrict__ bk,
    const float* __restrict__ bv, float* __restrict__ bqkv)
{
    __shared__ float tile[32][33];
    int blk = blockIdx.x, t = threadIdx.x;
    if (blk < itemBlocks) {
        int i = blk*256 + t;
        float4 v = ((const float4*)item_emb)[i];
        ushort4 h; h.x=f2b(v.x); h.y=f2b(v.y); h.z=f2b(v.z); h.w=f2b(v.w);
        ((ushort4*)item_b)[i] = h;
        return;
    }
    blk -= itemBlocks;
    if (blk < 64)       wtr_body(Wq, 256, 256,  WqkvT,            blk & 7,  blk >> 3, tile, t);
    else if (blk < 128) wtr_body(Wk, 256, 256,  WqkvT + 256*256, (blk-64) & 7,  (blk-64) >> 3, tile, t);
    else if (blk < 192) wtr_body(Wv, 256, 256,  WqkvT + 512*256, (blk-128) & 7, (blk-128) >> 3, tile, t);
    else if (blk < 256) wtr_body(Wo, 256, 256,  WoT,             (blk-192) & 7, (blk-192) >> 3, tile, t);
    else if (blk < 512) { int id = blk-256; wtr_body(W1, 256, 1024, W1T, id & 31, id >> 5, tile, t); }
    else if (blk < 768) { int id = blk-512; wtr_body(W2, 1024, 256, W2T, id & 7,  id >> 3, tile, t); }
    else { bqkv[t] = bq[t]; bqkv[256+t] = bk[t]; bqkv[512+t] = bv[t]; }
}

// ============ intra-session attention via MFMA ============================
#define XST 264
__global__ __launch_bounds__(256) void intra_k(
    const float* __restrict__ item_emb, const unsigned short* __restrict__ item_b,
    const int* __restrict__ sess,
    float* __restrict__ S, float* __restrict__ u_short)
{
    __shared__ __align__(16) unsigned short xb[4][INTRA][XST];
    __shared__ __align__(16) unsigned short zrow[XST];
    __shared__ float sc[4][20][21];
    __shared__ float wsum[4][20];
    __shared__ int ids[4][INTRA];
    int t = threadIdx.x, w = t >> 6, lane = t & 63;
    int s = blockIdx.x*4 + w;
    if (lane < INTRA) ids[w][lane] = sess[s*INTRA + lane];
    if (t < 132) ((unsigned int*)zrow)[t] = 0u;
    __syncthreads();
    int col = lane*4;
    for (int r = 0; r < INTRA; ++r) {
        int id = ids[w][r];
        ushort4 h;
        if (id == 0) { h.x=h.y=h.z=h.w=0; }
        else if (item_b) {
            h = *(const ushort4*)(item_b + (size_t)id*D + col);
        } else {
            float4 v4 = *(const float4*)(item_emb + (size_t)id*D + col);
            h.x=f2b(v4.x); h.y=f2b(v4.y); h.z=f2b(v4.z); h.w=f2b(v4.w);
        }
        *(ushort4*)&xb[w][r][col] = h;
    }
    __syncthreads();
    int ml = lane & 15, q8 = (lane >> 4) * 8;
    int r1 = 16 + ml;
    f32x4 acc[2][2] = {};
    for (int k0 = 0; k0 < D; k0 += 32) {
        bf16x8 fr0 = *(const bf16x8*)&xb[w][ml][k0 + q8];
        bf16x8 fr1 = (r1 < INTRA) ? *(const bf16x8*)&xb[w][r1][k0 + q8]
                                  : *(const bf16x8*)&zrow[q8];
        acc[0][0] = __builtin_amdgcn_mfma_f32_16x16x32_bf16(fr0, fr0, acc[0][0], 0,0,0);
        acc[0][1] = __builtin_amdgcn_mfma_f32_16x16x32_bf16(fr0, fr1, acc[0][1], 0,0,0);
        acc[1][0] = __builtin_amdgcn_mfma_f32_16x16x32_bf16(fr1, fr0, acc[1][0], 0,0,0);
        acc[1][1] = __builtin_amdgcn_mfma_f32_16x16x32_bf16(fr1, fr1, acc[1][1], 0,0,0);
    }
    int rb = (lane >> 4) * 4;
    #pragma unroll
    for (int mt = 0; mt < 2; ++mt)
        #pragma unroll
        for (int nt = 0; nt < 2; ++nt)
            #pragma unroll
            for (int i = 0; i < 4; ++i) {
                int row = mt*16 + rb + i, cc = nt*16 + ml;
                if (row < INTRA && cc < INTRA) sc[w][row][cc] = acc[mt][nt][i];
            }
    __syncthreads();
    if (lane < INTRA) {
        float vrow[INTRA]; float mx = -1e30f;
        #pragma unroll
        for (int k = 0; k < INTRA; ++k) {
            float v_ = (ids[w][k] != 0) ? sc[w][lane][k]*(1.0f/16.0f) : -1e9f;
            vrow[k] = v_; mx = fmaxf(mx, v_);
        }
        float ssum = 0.f;
        #pragma unroll
        for (int k = 0; k < INTRA; ++k) { float e_ = expf(vrow[k]-mx); vrow[k]=e_; ssum+=e_; }
        float inv = 1.f/ssum;
        #pragma unroll
        for (int k = 0; k < INTRA; ++k) sc[w][lane][k] = vrow[k]*inv;
    }
    __syncthreads();
    if (lane < INTRA) {
        float s_ = 0.f;
        #pragma unroll
        for (int q = 0; q < INTRA; ++q) s_ += sc[w][q][lane];
        wsum[w][lane] = s_;
    }
    __syncthreads();
    float4 v = {0.f,0.f,0.f,0.f};
    #pragma unroll
    for (int k = 0; k < INTRA; ++k) {
        float ws_ = wsum[w][k];
        ushort4 h = *(const ushort4*)&xb[w][k][col];
        v.x += ws_*b2f(h.x); v.y += ws_*b2f(h.y);
        v.z += ws_*b2f(h.z); v.w += ws_*b2f(h.w);
    }
    int b = s / INTER, srow = s % INTER;
    if (srow == INTER-1) *(float4*)(u_short + (size_t)b*D + col) = v;
    const float kc = -9.210340371976184f / 256.0f;
    float div0 = expf((float)col * kc);
    float div2 = expf((float)(col+2) * kc);
    float4 o;
    o.x = v.x + sinf((float)srow * div0);
    o.y = v.y + cosf((float)srow * div0);
    o.z = v.z + sinf((float)srow * div2);
    o.w = v.w + cosf((float)srow * div2);
    *(float4*)(S + (size_t)s*D + col) = o;
}

// ============ layernorm (ddof=1): wave per row, shuffle-only ==============
__global__ __launch_bounds__(256) void ln4_k(const float* __restrict__ X,
    const float* __restrict__ g, const float* __restrict__ bb,
    unsigned short* __restrict__ Yb, float* __restrict__ Yf)
{
    int w = threadIdx.x >> 6, lane = threadIdx.x & 63;
    size_t row = (size_t)blockIdx.x*4 + w;
    int col = lane*4;
    float4 x = *(const float4*)(X + row*D + col);
    float s_ = x.x + x.y + x.z + x.w;
    #pragma unroll
    for (int off = 32; off > 0; off >>= 1) s_ += __shfl_xor(s_, off, 64);
    float mean = s_ * (1.f/256.f);
    float4 d0; d0.x = x.x-mean; d0.y = x.y-mean; d0.z = x.z-mean; d0.w = x.w-mean;
    float q_ = d0.x*d0.x + d0.y*d0.y + d0.z*d0.z + d0.w*d0.w;
    #pragma unroll
    for (int off = 32; off > 0; off >>= 1) q_ += __shfl_xor(q_, off, 64);
    float inv = 1.f/(sqrtf(q_ * (1.f/255.f)) + 1e-6f);
    float4 g4 = *(const float4*)(g + col), b4 = *(const float4*)(bb + col);
    float4 y;
    y.x = g4.x*d0.x*inv + b4.x; y.y = g4.y*d0.y*inv + b4.y;
    y.z = g4.z*d0.z*inv + b4.z; y.w = g4.w*d0.w*inv + b4.w;
    if (Yb) {
        ushort4 h; h.x=f2b(y.x); h.y=f2b(y.y); h.z=f2b(y.z); h.w=f2b(y.w);
        *(ushort4*)(Yb + row*D + col) = h;
    } else {
        *(float4*)(Yf + row*D + col) = y;
    }
}

// ============ bf16 MFMA GEMM: 128x128 tile, BK=64 (two 32-sub-buffers) ====
#define TM 128
#define TN 128
__global__ __launch_bounds__(256) void mgemm_k(
    const unsigned short* __restrict__ A, int lda,
    const unsigned short* __restrict__ BT,
    const float* __restrict__ bias,
    float* __restrict__ Cf, unsigned short* __restrict__ Cb,
    int ldc, int K, int flags)   // bit0: fp32 accum into Cf, bit1: relu
{
    __shared__ __align__(16) unsigned short As[2][TM*32];
    __shared__ __align__(16) unsigned short Bs[2][TN*32];
    int tid = threadIdx.x;
    int lane = tid & 63, w = tid >> 6;
    int wrow = (w >> 1) * 64, wcol = (w & 1) * 64;
    int tile_m = blockIdx.y * TM, tile_n = blockIdx.x * TN;
    f32x4 acc[4][4] = {};
    const int r_in_chunk = lane >> 2;
    const int e_in_row = (lane & 3) * 8;   // elems (16B)
    const int qoff = (lane >> 4) * 8;
    const int ml = lane & 15;
    for (int k0 = 0; k0 < K; k0 += 64) {
        #pragma unroll
        for (int h = 0; h < 2; ++h) {
            #pragma unroll
            for (int i = 0; i < 2; ++i) {
                int c = w*2 + i;
                int row = c*16 + r_in_chunk;
                gl_lds16(A + (size_t)(tile_m + row)*lda + k0 + h*32 + e_in_row,
                         (char*)As[h] + c*1024 + lane*16);
            }
            #pragma unroll
            for (int i = 0; i < 2; ++i) {
                int c = w*2 + i;
                int row = c*16 + r_in_chunk;
                gl_lds16(BT + (size_t)(tile_n + row)*K + k0 + h*32 + e_in_row,
                         (char*)Bs[h] + c*1024 + lane*16);
            }
        }
        __syncthreads();
        #pragma unroll
        for (int h = 0; h < 2; ++h) {
            bf16x8 af[4], bfr[4];
            #pragma unroll
            for (int mt = 0; mt < 4; ++mt)
                af[mt] = *(const bf16x8*)(As[h] + (wrow + mt*16 + ml)*32 + qoff);
            #pragma unroll
            for (int nt = 0; nt < 4; ++nt)
                bfr[nt] = *(const bf16x8*)(Bs[h] + (wcol + nt*16 + ml)*32 + qoff);
            #pragma unroll
            for (int mt = 0; mt < 4; ++mt)
                #pragma unroll
                for (int nt = 0; nt < 4; ++nt)
                    acc[mt][nt] = __builtin_amdgcn_mfma_f32_16x16x32_bf16(
                        af[mt], bfr[nt], acc[mt][nt], 0, 0, 0);
        }
        __syncthreads();
    }
    int col_l = lane & 15, rbase = (lane >> 4) * 4;
    #pragma unroll
    for (int mt = 0; mt < 4; ++mt) {
        #pragma unroll
        for (int nt = 0; nt < 4; ++nt) {
            int col = tile_n + wcol + nt*16 + col_l;
            float bs = bias ? bias[col] : 0.f;
            #pragma unroll
            for (int i = 0; i < 4; ++i) {
                size_t row = tile_m + wrow + mt*16 + rbase + i;
                float v_ = acc[mt][nt][i] + bs;
                if (flags & 2) v_ = fmaxf(v_, 0.f);
                if (flags & 1) Cf[row*ldc + col] += v_;
                else           Cb[row*ldc + col] = f2b(v_);
            }
        }
    }
}

// ============ inter-session MHA via MFMA: block per (b,h) =================
#define AST 40
#define PST 72
__global__ __launch_bounds__(256) void att_k(
    const unsigned short* __restrict__ QKV, const int* __restrict__ sess,
    unsigned short* __restrict__ O)
{
    __shared__ __align__(16) unsigned short qs[64][AST];
    __shared__ __align__(16) unsigned short ks[64][AST];
    __shared__ __align__(16) unsigned short vst[32][PST];
    __shared__ __align__(16) unsigned short pb[64][PST];
    __shared__ float p[50][52];
    __shared__ float msk[52];
    int b = blockIdx.x >> 3, h = blockIdx.x & 7;
    int t = threadIdx.x, w = t >> 6, lane = t & 63;
    for (int u = t; u < 400; u += 256) {
        int arr = u / 200, rem = u % 200, row = rem >> 2, part = rem & 3;
        const unsigned short* src = QKV + ((size_t)(b*INTER+row))*768 + arr*256 + h*32 + part*8;
        ushort4 a = *(const ushort4*)src, c = *(const ushort4*)(src+4);
        unsigned short* dst = (arr ? ks[row] : qs[row]) + part*8;
        *(ushort4*)dst = a; *(ushort4*)(dst+4) = c;
    }
    for (int u = t; u < INTER*32; u += 256) {
        int row = u >> 5, e = u & 31;
        vst[e][row] = QKV[((size_t)(b*INTER+row))*768 + 512 + h*32 + e];
    }
    for (int u = t; u < 32*14; u += 256) {
        int e = u / 14, k = 50 + (u % 14);
        vst[e][k] = 0;
    }
    for (int u = t; u < 64*14; u += 256) {
        int r = u / 14, k = 50 + (u % 14);
        pb[r][k] = 0;
    }
    if (t < INTER) msk[t] = (sess[(b*INTER + t)*INTRA] != 0) ? 1.f : 0.f;
    __syncthreads();
    int ml = lane & 15, q8 = (lane >> 4) * 8, rb = (lane >> 4) * 4;
    {
        bf16x8 afq = *(const bf16x8*)&qs[w*16 + ml][q8];
        #pragma unroll
        for (int nt = 0; nt < 4; ++nt) {
            bf16x8 bfk = *(const bf16x8*)&ks[nt*16 + ml][q8];
            f32x4 a0 = {};
            a0 = __builtin_amdgcn_mfma_f32_16x16x32_bf16(afq, bfk, a0, 0, 0, 0);
            #pragma unroll
            for (int i = 0; i < 4; ++i) {
                int row = w*16 + rb + i, cc = nt*16 + ml;
                if (row < INTER && cc < INTER)
                    p[row][cc] = (msk[cc] != 0.f) ? a0[i]*0.17677669529663687f : -1e9f;
            }
        }
    }
    __syncthreads();
    {
        int r0 = w*13, r1 = r0+13; if (r1 > INTER) r1 = INTER;
        for (int r = r0; r < r1; ++r) {
            float v = (lane < INTER) ? p[r][lane] : -1e30f;
            float m = v;
            #pragma unroll
            for (int off = 32; off > 0; off >>= 1) m = fmaxf(m, __shfl_xor(m, off, 64));
            float e_ = (lane < INTER) ? expf(v - m) : 0.f;
            float ssum = e_;
            #pragma unroll
            for (int off = 32; off > 0; off >>= 1) ssum += __shfl_xor(ssum, off, 64);
            if (lane < INTER) pb[r][lane] = f2b(e_ / ssum);
        }
    }
    __syncthreads();
    f32x4 acco[2] = {};
    #pragma unroll
    for (int kt = 0; kt < 2; ++kt) {
        bf16x8 ap = *(const bf16x8*)&pb[w*16 + ml][kt*32 + q8];
        #pragma unroll
        for (int nt = 0; nt < 2; ++nt) {
            bf16x8 bv = *(const bf16x8*)&vst[nt*16 + ml][kt*32 + q8];
            acco[nt] = __builtin_amdgcn_mfma_f32_16x16x32_bf16(ap, bv, acco[nt], 0, 0, 0);
        }
    }
    #pragma unroll
    for (int nt = 0; nt < 2; ++nt)
        #pragma unroll
        for (int i = 0; i < 4; ++i) {
            int row = w*16 + rb + i, cc = nt*16 + ml;
            if (row < INTER)
                O[((size_t)(b*INTER+row))*D + h*DH + cc] = f2b(acco[nt][i]);
        }
}

// ============ fused tail: final LN + u_long + gate ========================
__global__ __launch_bounds__(256) void tail_k(
    const float* __restrict__ S,
    const float* __restrict__ fn_g, const float* __restrict__ fn_b,
    const float* __restrict__ user_emb, const int* __restrict__ us,
    const float* __restrict__ time_emb, const int* __restrict__ tdlt,
    const float* __restrict__ u_short,
    const float* __restrict__ Wl, const float* __restrict__ Ws,
    const float* __restrict__ Wt, const float* __restrict__ gb,
    float* __restrict__ U)
{
    __shared__ float part[4][D];
    __shared__ float ul[D], ush[D], te[D];
    int b = blockIdx.x, t = threadIdx.x, w = t >> 6, lane = t & 63;
    int col = lane*4;
    float4 g4 = *(const float4*)(fn_g + col);
    float4 b4 = *(const float4*)(fn_b + col);
    float4 acc4 = {0.f,0.f,0.f,0.f};
    for (int l = w; l < INTER; l += 4) {
        float4 x = *(const float4*)(S + (size_t)(b*INTER + l)*D + col);
        float s = x.x + x.y + x.z + x.w;
        #pragma unroll
        for (int o = 32; o > 0; o >>= 1) s += __shfl_xor(s, o, 64);
        float mean = s * (1.f/256.f);
        float dx = x.x - mean, dy = x.y - mean, dz = x.z - mean, dw = x.w - mean;
        float q = dx*dx + dy*dy + dz*dz + dw*dw;
        #pragma unroll
        for (int o = 32; o > 0; o >>= 1) q += __shfl_xor(q, o, 64);
        float inv = 1.f/(sqrtf(q*(1.f/255.f)) + 1e-6f);
        acc4.x += g4.x*dx*inv + b4.x;
        acc4.y += g4.y*dy*inv + b4.y;
        acc4.z += g4.z*dz*inv + b4.z;
        acc4.w += g4.w*dw*inv + b4.w;
    }
    *(float4*)&part[w][col] = acc4;
    __syncthreads();
    int id = us[b];
    float ue = (id == 0) ? 0.f : user_emb[(size_t)id*D + t];
    float ulv = part[0][t] + part[1][t] + part[2][t] + part[3][t] + ue;
    ul[t]  = ulv;
    float ushv = u_short[b*D + t];
    ush[t] = ushv;
    te[t]  = time_emb[(size_t)tdlt[b]*D + t];
    __syncthreads();
    float a = gb[t];
    for (int k = 0; k < D; ++k)
        a += ul[k]*Wl[k*D + t] + ush[k]*Ws[k*D + t] + te[k]*Wt[k*D + t];
    float tg = 1.f/(1.f + expf(-a));
    U[b*D + t] = tg*ushv + (1.f - tg)*ulv;
}

// ============ candidate scoring ===========================================
__global__ __launch_bounds__(256) void out_k(
    const float* __restrict__ item_emb, const unsigned short* __restrict__ item_b,
    const int* __restrict__ pred,
    const float* __restrict__ U, float* __restrict__ out)
{
    int b = blockIdx.x >> 6;
    int cbase = (blockIdx.x & 63) * 32;
    int t = threadIdx.x, w = t >> 6, lane = t & 63;
    int hl = lane & 31, half = lane >> 5;
    float4 u0 = *(const float4*)(U + (size_t)b*D + hl*8);
    float4 u1 = *(const float4*)(U + (size_t)b*D + hl*8 + 4);
    for (int it = 0; it < 4; ++it) {
        int c = cbase + it*8 + w*2 + half;
        int id = pred[b*CANDN + c];
        float p = 0.f;
        if (id) {
            if (item_b) {
                const unsigned short* row = item_b + (size_t)id*D + hl*8;
                ushort4 a = *(const ushort4*)row;
                ushort4 d = *(const ushort4*)(row+4);
                p = b2f(a.x)*u0.x + b2f(a.y)*u0.y + b2f(a.z)*u0.z + b2f(a.w)*u0.w
                  + b2f(d.x)*u1.x + b2f(d.y)*u1.y + b2f(d.z)*u1.z + b2f(d.w)*u1.w;
            } else {
                const float* row = item_emb + (size_t)id*D + hl*8;
                float4 a = *(const float4*)row;
                float4 d = *(const float4*)(row+4);
                p = a.x*u0.x + a.y*u0.y + a.z*u0.z + a.w*u0.w
                  + d.x*u1.x + d.y*u1.y + d.z*u1.z + d.w*u1.w;
            }
        }
        #pragma unroll
        for (int off = 16; off > 0; off >>= 1) p += __shfl_xor(p, off, 64);
        if (hl == 0) out[b*CANDN + c] = p;
    }
}

// ---------------------------------------------------------------------------
extern "C" void kernel_launch(void* const* d_in, const int* in_sizes, int n_in,
                              void* d_out, int out_size, void* d_ws, size_t ws_size,
                              hipStream_t stream)
{
    const float* item_emb = (const float*)d_in[0];
    const float* user_emb = (const float*)d_in[1];
    const float* time_emb = (const float*)d_in[2];
    const float* Wq = (const float*)d_in[3];  const float* bq = (const float*)d_in[4];
    const float* Wk = (const float*)d_in[5];  const float* bk = (const float*)d_in[6];
    const float* Wv = (const float*)d_in[7];  const float* bv = (const float*)d_in[8];
    const float* Wo = (const float*)d_in[9];  const float* bo = (const float*)d_in[10];
    const float* ln1_g = (const float*)d_in[11]; const float* ln1_b = (const float*)d_in[12];
    const float* W1 = (const float*)d_in[13]; const float* b1 = (const float*)d_in[14];
    const float* W2 = (const float*)d_in[15]; const float* b2 = (const float*)d_in[16];
    const float* ln2_g = (const float*)d_in[17]; const float* ln2_b = (const float*)d_in[18];
    const float* fn_g = (const float*)d_in[19]; const float* fn_b = (const float*)d_in[20];
    const float* gWl = (const float*)d_in[21]; const float* gWs = (const float*)d_in[22];
    const float* gWt = (const float*)d_in[23]; const float* gbias = (const float*)d_in[24];
    const int* us   = (const int*)d_in[25];
    const int* sess = (const int*)d_in[26];
    const int* tdlt = (const int*)d_in[27];
    const int* pred = (const int*)d_in[28];
    float* out = (float*)d_out;

    char* base = (char*)d_ws;
    size_t off = 0;
    float* S = (float*)(base+off);              off += (size_t)ROWS*D*4;
    unsigned short* Ybf = (unsigned short*)(base+off); off += (size_t)ROWS*D*2;
    unsigned short* QKVb = (unsigned short*)(base+off);
    unsigned short* Hb = QKVb;
    off += (size_t)ROWS*1024*2;
    unsigned short* WqkvT = (unsigned short*)(base+off); off += (size_t)768*256*2;
    unsigned short* WoT   = (unsigned short*)(base+off); off += (size_t)256*256*2;
    unsigned short* W1T   = (unsigned short*)(base+off); off += (size_t)1024*256*2;
    unsigned short* W2T   = (unsigned short*)(base+off); off += (size_t)256*1024*2;
    float* bqkv = (float*)(base+off);            off += 768*4;
    float* u_short = (float*)(base+off);         off += BSZ*D*4;
    float* u_long  = (float*)(base+off);         off += BSZ*D*4;
    float* Ufin    = (float*)(base+off);         off += BSZ*D*4;
    (void)u_long;
    unsigned short* item_b = (unsigned short*)(base+off);
    size_t item_b_bytes = (size_t)NITEMS*D*2;
    bool use_b16 = (off + item_b_bytes) <= ws_size;
    if (!use_b16) item_b = nullptr;

    // 0. prep: item table + weight transposes + bias concat (one kernel)
    int itemBlocks = use_b16 ? (NITEMS*D/4)/256 : 0;
    prep_k<<<itemBlocks + 769, 256, 0, stream>>>(
        item_emb, item_b, itemBlocks,
        Wq, Wk, Wv, Wo, W1, W2,
        WqkvT, WoT, W1T, W2T,
        bq, bk, bv, bqkv);

    // 1. intra-session attention (MFMA)
    intra_k<<<ROWS/4, 256, 0, stream>>>(item_emb, item_b, sess, S, u_short);

    // 2. transformer blocks
    for (int blk = 0; blk < 2; ++blk) {
        ln4_k<<<ROWS/4, 256, 0, stream>>>(S, ln1_g, ln1_b, Ybf, nullptr);
        mgemm_k<<<dim3(6,100), 256, 0, stream>>>(Ybf, D, WqkvT, bqkv,
                                                 nullptr, QKVb, 768, 256, 0);
        att_k<<<BSZ*HEADS, 256, 0, stream>>>(QKVb, sess, Ybf);
        mgemm_k<<<dim3(2,100), 256, 0, stream>>>(Ybf, D, WoT, bo,
                                                 S, nullptr, 256, 256, 1);
        ln4_k<<<ROWS/4, 256, 0, stream>>>(S, ln2_g, ln2_b, Ybf, nullptr);
        mgemm_k<<<dim3(8,100), 256, 0, stream>>>(Ybf, D, W1T, b1,
                                                 nullptr, Hb, 1024, 256, 2);
        mgemm_k<<<dim3(2,100), 256, 0, stream>>>(Hb, 1024, W2T, b2,
                                                 S, nullptr, 256, 1024, 1);
    }

    // 3. fused tail: final LN + u_long + gate
    tail_k<<<BSZ, 256, 0, stream>>>(S, fn_g, fn_b, user_emb, us,
        time_emb, tdlt, u_short, gWl, gWs, gWt, gbias, Ufin);

    // 4. candidate scores
    out_k<<<(BSZ*CANDN)/32, 256, 0, stream>>>(item_emb, item_b, pred, Ufin, out);
}

// Round 3
// 677.414 us; speedup vs baseline: 1.5009x; 1.2366x over previous
//
#include <hip/hip_runtime.h>
#include <math.h>

#define D 256
#define HEADS 8
#define DH 32
#define INTER 50
#define INTRA 20
#define BSZ 256
#define CANDN 2048
#define ROWS (BSZ*INTER)   // 12800
#define NITEMS 200000

typedef unsigned short ushort_t;
typedef __attribute__((ext_vector_type(8))) short bf16x8;
typedef __attribute__((ext_vector_type(4))) float f32x4;

__device__ __forceinline__ unsigned short f2b(float f) {
    union { float f; unsigned u; } v; v.f = f;
    unsigned r = v.u + 0x7fffu + ((v.u >> 16) & 1u);
    return (unsigned short)(r >> 16);
}
__device__ __forceinline__ float b2f(unsigned short h) {
    union { unsigned u; float f; } v; v.u = ((unsigned)h) << 16;
    return v.f;
}

// ============ prep: item fp32->bf16 table + 6 weight transposes + bcat ====
__device__ __forceinline__ void wtr_body(const float* __restrict__ W, int K, int N,
    unsigned short* __restrict__ WT, int bx, int by, float (*tile)[33], int t)
{
    int n0 = bx*32, k0 = by*32;
    int tx = t & 31, ty = t >> 5;
    for (int i = ty; i < 32; i += 8)
        tile[i][tx] = W[(size_t)(k0+i)*N + n0 + tx];
    __syncthreads();
    for (int i = ty; i < 32; i += 8)
        WT[(size_t)(n0+i)*K + k0 + tx] = f2b(tile[tx][i]);
}

__global__ __launch_bounds__(256) void prep_k(
    const float* __restrict__ item_emb, unsigned short* __restrict__ item_b, int itemBlocks,
    const float* __restrict__ Wq, const float* __restrict__ Wk,
    const float* __restrict__ Wv, const float* __restrict__ Wo,
    const float* __restrict__ W1, const float* __restrict__ W2,
    unsigned short* __restrict__ WqkvT, unsigned short* __restrict__ WoT,
    unsigned short* __restrict__ W1T, unsigned short* __restrict__ W2T,
    const float* __restrict__ bq, const float* __restrict__ bk,
    const float* __restrict__ bv, float* __restrict__ bqkv)
{
    __shared__ float tile[32][33];
    int blk = blockIdx.x, t = threadIdx.x;
    if (blk < itemBlocks) {
        int i = blk*256 + t;
        float4 v = ((const float4*)item_emb)[i];
        ushort4 h; h.x=f2b(v.x); h.y=f2b(v.y); h.z=f2b(v.z); h.w=f2b(v.w);
        ((ushort4*)item_b)[i] = h;
        return;
    }
    blk -= itemBlocks;
    if (blk < 64)       wtr_body(Wq, 256, 256,  WqkvT,            blk & 7,  blk >> 3, tile, t);
    else if (blk < 128) wtr_body(Wk, 256, 256,  WqkvT + 256*256, (blk-64) & 7,  (blk-64) >> 3, tile, t);
    else if (blk < 192) wtr_body(Wv, 256, 256,  WqkvT + 512*256, (blk-128) & 7, (blk-128) >> 3, tile, t);
    else if (blk < 256) wtr_body(Wo, 256, 256,  WoT,             (blk-192) & 7, (blk-192) >> 3, tile, t);
    else if (blk < 512) { int id = blk-256; wtr_body(W1, 256, 1024, W1T, id & 31, id >> 5, tile, t); }
    else if (blk < 768) { int id = blk-512; wtr_body(W2, 1024, 256, W2T, id & 7,  id >> 3, tile, t); }
    else { bqkv[t] = bq[t]; bqkv[256+t] = bk[t]; bqkv[512+t] = bv[t]; }
}

// ============ intra-session attention via MFMA ============================
#define XST 264
__global__ __launch_bounds__(256) void intra_k(
    const float* __restrict__ item_emb, const unsigned short* __restrict__ item_b,
    const int* __restrict__ sess,
    float* __restrict__ S, float* __restrict__ u_short)
{
    __shared__ __align__(16) unsigned short xb[4][INTRA][XST];
    __shared__ __align__(16) unsigned short zrow[XST];
    __shared__ float sc[4][20][21];
    __shared__ float wsum[4][20];
    __shared__ int ids[4][INTRA];
    int t = threadIdx.x, w = t >> 6, lane = t & 63;
    int s = blockIdx.x*4 + w;
    if (lane < INTRA) ids[w][lane] = sess[s*INTRA + lane];
    if (t < 132) ((unsigned int*)zrow)[t] = 0u;
    __syncthreads();
    int col = lane*4;
    for (int r = 0; r < INTRA; ++r) {
        int id = ids[w][r];
        ushort4 h;
        if (id == 0) { h.x=h.y=h.z=h.w=0; }
        else if (item_b) {
            h = *(const ushort4*)(item_b + (size_t)id*D + col);
        } else {
            float4 v4 = *(const float4*)(item_emb + (size_t)id*D + col);
            h.x=f2b(v4.x); h.y=f2b(v4.y); h.z=f2b(v4.z); h.w=f2b(v4.w);
        }
        *(ushort4*)&xb[w][r][col] = h;
    }
    __syncthreads();
    int ml = lane & 15, q8 = (lane >> 4) * 8;
    int r1 = 16 + ml;
    f32x4 acc[2][2] = {};
    for (int k0 = 0; k0 < D; k0 += 32) {
        bf16x8 fr0 = *(const bf16x8*)&xb[w][ml][k0 + q8];
        bf16x8 fr1 = (r1 < INTRA) ? *(const bf16x8*)&xb[w][r1][k0 + q8]
                                  : *(const bf16x8*)&zrow[q8];
        acc[0][0] = __builtin_amdgcn_mfma_f32_16x16x32_bf16(fr0, fr0, acc[0][0], 0,0,0);
        acc[0][1] = __builtin_amdgcn_mfma_f32_16x16x32_bf16(fr0, fr1, acc[0][1], 0,0,0);
        acc[1][0] = __builtin_amdgcn_mfma_f32_16x16x32_bf16(fr1, fr0, acc[1][0], 0,0,0);
        acc[1][1] = __builtin_amdgcn_mfma_f32_16x16x32_bf16(fr1, fr1, acc[1][1], 0,0,0);
    }
    int rb = (lane >> 4) * 4;
    #pragma unroll
    for (int mt = 0; mt < 2; ++mt)
        #pragma unroll
        for (int nt = 0; nt < 2; ++nt)
            #pragma unroll
            for (int i = 0; i < 4; ++i) {
                int row = mt*16 + rb + i, cc = nt*16 + ml;
                if (row < INTRA && cc < INTRA) sc[w][row][cc] = acc[mt][nt][i];
            }
    __syncthreads();
    if (lane < INTRA) {
        float vrow[INTRA]; float mx = -1e30f;
        #pragma unroll
        for (int k = 0; k < INTRA; ++k) {
            float v_ = (ids[w][k] != 0) ? sc[w][lane][k]*(1.0f/16.0f) : -1e9f;
            vrow[k] = v_; mx = fmaxf(mx, v_);
        }
        float ssum = 0.f;
        #pragma unroll
        for (int k = 0; k < INTRA; ++k) { float e_ = expf(vrow[k]-mx); vrow[k]=e_; ssum+=e_; }
        float inv = 1.f/ssum;
        #pragma unroll
        for (int k = 0; k < INTRA; ++k) sc[w][lane][k] = vrow[k]*inv;
    }
    __syncthreads();
    if (lane < INTRA) {
        float s_ = 0.f;
        #pragma unroll
        for (int q = 0; q < INTRA; ++q) s_ += sc[w][q][lane];
        wsum[w][lane] = s_;
    }
    __syncthreads();
    float4 v = {0.f,0.f,0.f,0.f};
    #pragma unroll
    for (int k = 0; k < INTRA; ++k) {
        float ws_ = wsum[w][k];
        ushort4 h = *(const ushort4*)&xb[w][k][col];
        v.x += ws_*b2f(h.x); v.y += ws_*b2f(h.y);
        v.z += ws_*b2f(h.z); v.w += ws_*b2f(h.w);
    }
    int b = s / INTER, srow = s % INTER;
    if (srow == INTER-1) *(float4*)(u_short + (size_t)b*D + col) = v;
    const float kc = -9.210340371976184f / 256.0f;
    float div0 = expf((float)col * kc);
    float div2 = expf((float)(col+2) * kc);
    float4 o;
    o.x = v.x + sinf((float)srow * div0);
    o.y = v.y + cosf((float)srow * div0);
    o.z = v.z + sinf((float)srow * div2);
    o.w = v.w + cosf((float)srow * div2);
    *(float4*)(S + (size_t)s*D + col) = o;
}

// ============ mega transformer block: one block per batch element =========
// LDS regions (byte offsets), phase-reused:
//   VT   0      .. 36864   u16 [8][32][72]   (V^T per head; q 50..63 zeroed)
//   Y    36864  .. 70656   u16 [64][264]     (LN1 out, rows 50..63 zeroed)
//   Q    70656  .. 104448  u16 [64][264]     (rows 50..63 zeroed)
//   K    104448 .. 138240  u16 [64][264]     (rows 50..63 zeroed)
//   PB   36864  .. 110592  u16 [8][64][72]   (P bf16, overlays Y/Q/K after use)
//   O    110592 .. 144384  u16 [64][264]     (att out, overlays K tail)
//   SL   0      .. 52000   f32 [50][260]     (S residual, overlays VT after PV)
//   Y2   52000  .. 85792   u16 [64][264]     (LN2 out)
//   H    85792  .. 152352  u16 [64][520]     (FFN half, relu)
//   MSK  152352 .. 152608  f32 [64]
#define LB_VT 0
#define LB_Y 36864
#define LB_Q 70656
#define LB_K 104448
#define LB_PB 36864
#define LB_O 110592
#define LB_SL 0
#define LB_Y2 52000
#define LB_H 85792
#define LB_MSK 152352
#define MFMA16(a,b,c) __builtin_amdgcn_mfma_f32_16x16x32_bf16(a, b, c, 0, 0, 0)

__global__ __launch_bounds__(512) void block_k(
    float* __restrict__ S,
    const unsigned short* __restrict__ WqkvT, const float* __restrict__ bqkv,
    const unsigned short* __restrict__ WoT, const float* __restrict__ bo,
    const unsigned short* __restrict__ W1T, const float* __restrict__ b1,
    const unsigned short* __restrict__ W2T, const float* __restrict__ b2,
    const float* __restrict__ ln1_g, const float* __restrict__ ln1_b,
    const float* __restrict__ ln2_g, const float* __restrict__ ln2_b,
    const int* __restrict__ sess)
{
    __shared__ __align__(16) char LB[152608];
    unsigned short* Yp  = (unsigned short*)(LB + LB_Y);
    unsigned short* Qp  = (unsigned short*)(LB + LB_Q);
    unsigned short* Kp  = (unsigned short*)(LB + LB_K);
    unsigned short* VTp = (unsigned short*)(LB + LB_VT);
    unsigned short* Op  = (unsigned short*)(LB + LB_O);
    unsigned short* Y2p = (unsigned short*)(LB + LB_Y2);
    unsigned short* Hp  = (unsigned short*)(LB + LB_H);
    float* Slp  = (float*)(LB + LB_SL);
    float* mskp = (float*)(LB + LB_MSK);

    int b = blockIdx.x;
    int t = threadIdx.x, w = t >> 6, lane = t & 63;
    int ml = lane & 15, q8 = (lane >> 4) * 8;
    int col_l = ml, rbase = (lane >> 4) * 4;
    float* Sg = S + (size_t)b * INTER * D;

    // ---- phase 0: mask + zero pads ----
    if (t < 64) mskp[t] = (t < 50 && sess[(b*INTER + t)*INTRA] != 0) ? 1.f : 0.f;
    for (int u = t; u < 14*256; u += 512) {
        int r = 50 + (u >> 8), c = u & 255;
        Yp[r*264 + c] = 0; Qp[r*264 + c] = 0; Kp[r*264 + c] = 0;
    }
    for (int u = t; u < 8*32*14; u += 512) {
        int hh = u / 448, rem = u % 448;
        VTp[(hh*32 + rem/14)*72 + 50 + rem%14] = 0;
    }
    // ---- phase 1: LN1 (S global -> Y bf16) ----
    {
        int col = lane*4;
        float4 g4 = *(const float4*)(ln1_g + col), b4 = *(const float4*)(ln1_b + col);
        for (int r = w; r < 50; r += 8) {
            float4 x = *(const float4*)(Sg + r*256 + col);
            float s_ = x.x + x.y + x.z + x.w;
            #pragma unroll
            for (int o = 32; o > 0; o >>= 1) s_ += __shfl_xor(s_, o, 64);
            float mean = s_ * (1.f/256.f);
            float dx = x.x-mean, dy = x.y-mean, dz = x.z-mean, dw = x.w-mean;
            float qq = dx*dx + dy*dy + dz*dz + dw*dw;
            #pragma unroll
            for (int o = 32; o > 0; o >>= 1) qq += __shfl_xor(qq, o, 64);
            float inv = 1.f/(sqrtf(qq*(1.f/255.f)) + 1e-6f);
            ushort4 h;
            h.x = f2b(g4.x*dx*inv + b4.x); h.y = f2b(g4.y*dy*inv + b4.y);
            h.z = f2b(g4.z*dz*inv + b4.z); h.w = f2b(g4.w*dw*inv + b4.w);
            *(ushort4*)&Yp[r*264 + col] = h;
        }
    }
    __syncthreads();

    // ---- phase 2: QKV GEMM (Y @ WqkvT), wave w owns n-tiles w*6..w*6+5 ----
    {
        f32x4 acc[4][6] = {};
        #pragma unroll
        for (int ks = 0; ks < 8; ++ks) {
            bf16x8 af[4];
            #pragma unroll
            for (int mt = 0; mt < 4; ++mt)
                af[mt] = *(const bf16x8*)&Yp[(mt*16+ml)*264 + ks*32 + q8];
            bf16x8 bfr[6];
            #pragma unroll
            for (int j = 0; j < 6; ++j) {
                int n = (w*6 + j)*16 + ml;
                bfr[j] = *(const bf16x8*)(WqkvT + (size_t)n*256 + ks*32 + q8);
            }
            #pragma unroll
            for (int j = 0; j < 6; ++j)
                #pragma unroll
                for (int mt = 0; mt < 4; ++mt)
                    acc[mt][j] = MFMA16(af[mt], bfr[j], acc[mt][j]);
        }
        #pragma unroll
        for (int j = 0; j < 6; ++j) {
            int n = (w*6 + j)*16 + col_l;
            float bs = bqkv[n];
            #pragma unroll
            for (int mt = 0; mt < 4; ++mt)
                #pragma unroll
                for (int i = 0; i < 4; ++i) {
                    int row = mt*16 + rbase + i;
                    if (row < 50) {
                        unsigned short hv = f2b(acc[mt][j][i] + bs);
                        if (n < 256)      Qp[row*264 + n] = hv;
                        else if (n < 512) Kp[row*264 + (n-256)] = hv;
                        else { int hh=(n-512)>>5, e=(n-512)&31; VTp[(hh*32+e)*72 + row] = hv; }
                    }
                }
        }
    }
    __syncthreads();

    // ---- phase 3: QK^T (wave = head) + in-register softmax -> PB ----
    unsigned short* pbw = (unsigned short*)(LB + LB_PB + w*9216);  // [64][72]
    {
        f32x4 p3[4][4] = {};
        {
            bf16x8 af[4], bf_[4];
            #pragma unroll
            for (int mt = 0; mt < 4; ++mt)
                af[mt] = *(const bf16x8*)&Qp[(mt*16+ml)*264 + w*32 + q8];
            #pragma unroll
            for (int nt = 0; nt < 4; ++nt)
                bf_[nt] = *(const bf16x8*)&Kp[(nt*16+ml)*264 + w*32 + q8];
            #pragma unroll
            for (int mt = 0; mt < 4; ++mt)
                #pragma unroll
                for (int nt = 0; nt < 4; ++nt)
                    p3[mt][nt] = MFMA16(af[mt], bf_[nt], p3[mt][nt]);
        }
        float mk[4];
        #pragma unroll
        for (int nt = 0; nt < 4; ++nt) mk[nt] = mskp[nt*16 + ml];
        __syncthreads();   // Q/K reads done; PB region (overlays Y/Q/K) now writable
        #pragma unroll
        for (int mt = 0; mt < 4; ++mt)
            #pragma unroll
            for (int i = 0; i < 4; ++i) {
                int row = mt*16 + rbase + i;
                float v[4]; float m = -1e30f;
                #pragma unroll
                for (int nt = 0; nt < 4; ++nt) {
                    float x = (mk[nt] != 0.f) ? p3[mt][nt][i]*0.17677669529663687f : -1e9f;
                    v[nt] = x; m = fmaxf(m, x);
                }
                #pragma unroll
                for (int o = 8; o > 0; o >>= 1) m = fmaxf(m, __shfl_xor(m, o, 64));
                float s_ = 0.f;
                #pragma unroll
                for (int nt = 0; nt < 4; ++nt) { v[nt] = expf(v[nt] - m); s_ += v[nt]; }
                #pragma unroll
                for (int o = 8; o > 0; o >>= 1) s_ += __shfl_xor(s_, o, 64);
                float inv = 1.f / s_;
                if (row < 50) {
                    #pragma unroll
                    for (int nt = 0; nt < 4; ++nt)
                        pbw[row*72 + nt*16 + ml] = f2b(v[nt]*inv);
                }
            }
    }
    // ---- phase 4: PV (wave = head, reads own PB + VT) -> O ----
    {
        f32x4 po[4][2] = {};
        #pragma unroll
        for (int kt = 0; kt < 2; ++kt) {
            bf16x8 af[4], bv_[2];
            #pragma unroll
            for (int mt = 0; mt < 4; ++mt)
                af[mt] = *(const bf16x8*)&pbw[(mt*16+ml)*72 + kt*32 + q8];
            #pragma unroll
            for (int nt = 0; nt < 2; ++nt)
                bv_[nt] = *(const bf16x8*)&VTp[(w*32 + nt*16 + ml)*72 + kt*32 + q8];
            #pragma unroll
            for (int nt = 0; nt < 2; ++nt)
                #pragma unroll
                for (int mt = 0; mt < 4; ++mt)
                    po[mt][nt] = MFMA16(af[mt], bv_[nt], po[mt][nt]);
        }
        #pragma unroll
        for (int nt = 0; nt < 2; ++nt)
            #pragma unroll
            for (int mt = 0; mt < 4; ++mt)
                #pragma unroll
                for (int i = 0; i < 4; ++i) {
                    int row = mt*16 + rbase + i;
                    if (row < 50)
                        Op[row*264 + w*32 + nt*16 + col_l] = f2b(po[mt][nt][i]);
                }
    }
    __syncthreads();

    // ---- phase 5: Wo GEMM + residual -> SL (fp32, overlays VT/PB) ----
    {
        f32x4 a5[4][2] = {};
        #pragma unroll
        for (int ks = 0; ks < 8; ++ks) {
            bf16x8 af[4], bw[2];
            #pragma unroll
            for (int mt = 0; mt < 4; ++mt)
                af[mt] = *(const bf16x8*)&Op[(mt*16+ml)*264 + ks*32 + q8];
            #pragma unroll
            for (int j = 0; j < 2; ++j) {
                int n = w*32 + j*16 + ml;
                bw[j] = *(const bf16x8*)(WoT + (size_t)n*256 + ks*32 + q8);
            }
            #pragma unroll
            for (int j = 0; j < 2; ++j)
                #pragma unroll
                for (int mt = 0; mt < 4; ++mt)
                    a5[mt][j] = MFMA16(af[mt], bw[j], a5[mt][j]);
        }
        #pragma unroll
        for (int j = 0; j < 2; ++j) {
            int n = w*32 + j*16 + col_l;
            float bv = bo[n];
            #pragma unroll
            for (int mt = 0; mt < 4; ++mt)
                #pragma unroll
                for (int i = 0; i < 4; ++i) {
                    int row = mt*16 + rbase + i;
                    if (row < 50)
                        Slp[row*260 + n] = Sg[row*256 + n] + a5[mt][j][i] + bv;
                }
        }
    }
    __syncthreads();

    // ---- phase 6: LN2 (SL -> Y2 bf16) ----
    {
        int col = lane*4;
        float4 g4 = *(const float4*)(ln2_g + col), b4 = *(const float4*)(ln2_b + col);
        for (int r = w; r < 50; r += 8) {
            float4 x = *(const float4*)&Slp[r*260 + col];
            float s_ = x.x + x.y + x.z + x.w;
            #pragma unroll
            for (int o = 32; o > 0; o >>= 1) s_ += __shfl_xor(s_, o, 64);
            float mean = s_ * (1.f/256.f);
            float dx = x.x-mean, dy = x.y-mean, dz = x.z-mean, dw = x.w-mean;
            float qq = dx*dx + dy*dy + dz*dz + dw*dw;
            #pragma unroll
            for (int o = 32; o > 0; o >>= 1) qq += __shfl_xor(qq, o, 64);
            float inv = 1.f/(sqrtf(qq*(1.f/255.f)) + 1e-6f);
            ushort4 h;
            h.x = f2b(g4.x*dx*inv + b4.x); h.y = f2b(g4.y*dy*inv + b4.y);
            h.z = f2b(g4.z*dz*inv + b4.z); h.w = f2b(g4.w*dw*inv + b4.w);
            *(ushort4*)&Y2p[r*264 + col] = h;
        }
        for (int u = t; u < 14*256; u += 512) {
            int r = 50 + (u >> 8), c = u & 255;
            Y2p[r*264 + c] = 0;
        }
    }
    __syncthreads();

    // ---- phases 7/8: FFN in two 512-wide halves ----
    #pragma unroll
    for (int hf = 0; hf < 2; ++hf) {
        {   // W1 half: H = relu(Y2 @ W1T_half + b1_half)
            f32x4 a7[4][4] = {};
            #pragma unroll
            for (int ks = 0; ks < 8; ++ks) {
                bf16x8 af[4], bw[4];
                #pragma unroll
                for (int mt = 0; mt < 4; ++mt)
                    af[mt] = *(const bf16x8*)&Y2p[(mt*16+ml)*264 + ks*32 + q8];
                #pragma unroll
                for (int j = 0; j < 4; ++j) {
                    int n = hf*512 + w*64 + j*16 + ml;
                    bw[j] = *(const bf16x8*)(W1T + (size_t)n*256 + ks*32 + q8);
                }
                #pragma unroll
                for (int j = 0; j < 4; ++j)
                    #pragma unroll
                    for (int mt = 0; mt < 4; ++mt)
                        a7[mt][j] = MFMA16(af[mt], bw[j], a7[mt][j]);
            }
            #pragma unroll
            for (int j = 0; j < 4; ++j) {
                int nl = w*64 + j*16 + col_l;
                float bv = b1[hf*512 + nl];
                #pragma unroll
                for (int mt = 0; mt < 4; ++mt)
                    #pragma unroll
                    for (int i = 0; i < 4; ++i) {
                        int row = mt*16 + rbase + i;
                        if (row < 50)
                            Hp[row*520 + nl] = f2b(fmaxf(a7[mt][j][i] + bv, 0.f));
                    }
            }
        }
        __syncthreads();
        {   // W2 half: SL += H @ W2T_half (+ b2 once)
            f32x4 a8[4][2] = {};
            #pragma unroll
            for (int ks = 0; ks < 16; ++ks) {
                bf16x8 af[4], bw[2];
                #pragma unroll
                for (int mt = 0; mt < 4; ++mt)
                    af[mt] = *(const bf16x8*)&Hp[(mt*16+ml)*520 + ks*32 + q8];
                #pragma unroll
                for (int j = 0; j < 2; ++j) {
                    int n = w*32 + j*16 + ml;
                    bw[j] = *(const bf16x8*)(W2T + (size_t)n*1024 + hf*512 + ks*32 + q8);
                }
                #pragma unroll
                for (int j = 0; j < 2; ++j)
                    #pragma unroll
                    for (int mt = 0; mt < 4; ++mt)
                        a8[mt][j] = MFMA16(af[mt], bw[j], a8[mt][j]);
            }
            #pragma unroll
            for (int j = 0; j < 2; ++j) {
                int n = w*32 + j*16 + col_l;
                float bv = (hf == 0) ? b2[n] : 0.f;
                #pragma unroll
                for (int mt = 0; mt < 4; ++mt)
                    #pragma unroll
                    for (int i = 0; i < 4; ++i) {
                        int row = mt*16 + rbase + i;
                        if (row < 50)
                            Slp[row*260 + n] += a8[mt][j][i] + bv;
                    }
            }
        }
        __syncthreads();
    }

    // ---- final: SL -> S global ----
    for (int u = t; u < 50*256; u += 512) {
        int r = u >> 8, c = u & 255;
        Sg[r*256 + c] = Slp[r*260 + c];
    }
}

// ============ fused tail: final LN + u_long + gate ========================
__global__ __launch_bounds__(256) void tail_k(
    const float* __restrict__ S,
    const float* __restrict__ fn_g, const float* __restrict__ fn_b,
    const float* __restrict__ user_emb, const int* __restrict__ us,
    const float* __restrict__ time_emb, const int* __restrict__ tdlt,
    const float* __restrict__ u_short,
    const float* __restrict__ Wl, const float* __restrict__ Ws,
    const float* __restrict__ Wt, const float* __restrict__ gb,
    float* __restrict__ U)
{
    __shared__ float part[4][D];
    __shared__ float ul[D], ush[D], te[D];
    int b = blockIdx.x, t = threadIdx.x, w = t >> 6, lane = t & 63;
    int col = lane*4;
    float4 g4 = *(const float4*)(fn_g + col);
    float4 b4 = *(const float4*)(fn_b + col);
    float4 acc4 = {0.f,0.f,0.f,0.f};
    for (int l = w; l < INTER; l += 4) {
        float4 x = *(const float4*)(S + (size_t)(b*INTER + l)*D + col);
        float s = x.x + x.y + x.z + x.w;
        #pragma unroll
        for (int o = 32; o > 0; o >>= 1) s += __shfl_xor(s, o, 64);
        float mean = s * (1.f/256.f);
        float dx = x.x - mean, dy = x.y - mean, dz = x.z - mean, dw = x.w - mean;
        float q = dx*dx + dy*dy + dz*dz + dw*dw;
        #pragma unroll
        for (int o = 32; o > 0; o >>= 1) q += __shfl_xor(q, o, 64);
        float inv = 1.f/(sqrtf(q*(1.f/255.f)) + 1e-6f);
        acc4.x += g4.x*dx*inv + b4.x;
        acc4.y += g4.y*dy*inv + b4.y;
        acc4.z += g4.z*dz*inv + b4.z;
        acc4.w += g4.w*dw*inv + b4.w;
    }
    *(float4*)&part[w][col] = acc4;
    __syncthreads();
    int id = us[b];
    float ue = (id == 0) ? 0.f : user_emb[(size_t)id*D + t];
    float ulv = part[0][t] + part[1][t] + part[2][t] + part[3][t] + ue;
    ul[t]  = ulv;
    float ushv = u_short[b*D + t];
    ush[t] = ushv;
    te[t]  = time_emb[(size_t)tdlt[b]*D + t];
    __syncthreads();
    float a = gb[t];
    for (int k = 0; k < D; ++k)
        a += ul[k]*Wl[k*D + t] + ush[k]*Ws[k*D + t] + te[k]*Wt[k*D + t];
    float tg = 1.f/(1.f + expf(-a));
    U[b*D + t] = tg*ushv + (1.f - tg)*ulv;
}

// ============ candidate scoring ===========================================
__global__ __launch_bounds__(256) void out_k(
    const float* __restrict__ item_emb, const unsigned short* __restrict__ item_b,
    const int* __restrict__ pred,
    const float* __restrict__ U, float* __restrict__ out)
{
    int b = blockIdx.x >> 6;
    int cbase = (blockIdx.x & 63) * 32;
    int t = threadIdx.x, w = t >> 6, lane = t & 63;
    int hl = lane & 31, half = lane >> 5;
    float4 u0 = *(const float4*)(U + (size_t)b*D + hl*8);
    float4 u1 = *(const float4*)(U + (size_t)b*D + hl*8 + 4);
    for (int it = 0; it < 4; ++it) {
        int c = cbase + it*8 + w*2 + half;
        int id = pred[b*CANDN + c];
        float p = 0.f;
        if (id) {
            if (item_b) {
                const unsigned short* row = item_b + (size_t)id*D + hl*8;
                ushort4 a = *(const ushort4*)row;
                ushort4 d = *(const ushort4*)(row+4);
                p = b2f(a.x)*u0.x + b2f(a.y)*u0.y + b2f(a.z)*u0.z + b2f(a.w)*u0.w
                  + b2f(d.x)*u1.x + b2f(d.y)*u1.y + b2f(d.z)*u1.z + b2f(d.w)*u1.w;
            } else {
                const float* row = item_emb + (size_t)id*D + hl*8;
                float4 a = *(const float4*)row;
                float4 d = *(const float4*)(row+4);
                p = a.x*u0.x + a.y*u0.y + a.z*u0.z + a.w*u0.w
                  + d.x*u1.x + d.y*u1.y + d.z*u1.z + d.w*u1.w;
            }
        }
        #pragma unroll
        for (int off = 16; off > 0; off >>= 1) p += __shfl_xor(p, off, 64);
        if (hl == 0) out[b*CANDN + c] = p;
    }
}

// ---------------------------------------------------------------------------
extern "C" void kernel_launch(void* const* d_in, const int* in_sizes, int n_in,
                              void* d_out, int out_size, void* d_ws, size_t ws_size,
                              hipStream_t stream)
{
    const float* item_emb = (const float*)d_in[0];
    const float* user_emb = (const float*)d_in[1];
    const float* time_emb = (const float*)d_in[2];
    const float* Wq = (const float*)d_in[3];  const float* bq = (const float*)d_in[4];
    const float* Wk = (const float*)d_in[5];  const float* bk = (const float*)d_in[6];
    const float* Wv = (const float*)d_in[7];  const float* bv = (const float*)d_in[8];
    const float* Wo = (const float*)d_in[9];  const float* bo = (const float*)d_in[10];
    const float* ln1_g = (const float*)d_in[11]; const float* ln1_b = (const float*)d_in[12];
    const float* W1 = (const float*)d_in[13]; const float* b1 = (const float*)d_in[14];
    const float* W2 = (const float*)d_in[15]; const float* b2 = (const float*)d_in[16];
    const float* ln2_g = (const float*)d_in[17]; const float* ln2_b = (const float*)d_in[18];
    const float* fn_g = (const float*)d_in[19]; const float* fn_b = (const float*)d_in[20];
    const float* gWl = (const float*)d_in[21]; const float* gWs = (const float*)d_in[22];
    const float* gWt = (const float*)d_in[23]; const float* gbias = (const float*)d_in[24];
    const int* us   = (const int*)d_in[25];
    const int* sess = (const int*)d_in[26];
    const int* tdlt = (const int*)d_in[27];
    const int* pred = (const int*)d_in[28];
    float* out = (float*)d_out;

    char* base = (char*)d_ws;
    size_t off = 0;
    float* S = (float*)(base+off);              off += (size_t)ROWS*D*4;
    unsigned short* WqkvT = (unsigned short*)(base+off); off += (size_t)768*256*2;
    unsigned short* WoT   = (unsigned short*)(base+off); off += (size_t)256*256*2;
    unsigned short* W1T   = (unsigned short*)(base+off); off += (size_t)1024*256*2;
    unsigned short* W2T   = (unsigned short*)(base+off); off += (size_t)256*1024*2;
    float* bqkv = (float*)(base+off);            off += 768*4;
    float* u_short = (float*)(base+off);         off += BSZ*D*4;
    float* Ufin    = (float*)(base+off);         off += BSZ*D*4;
    unsigned short* item_b = (unsigned short*)(base+off);
    size_t item_b_bytes = (size_t)NITEMS*D*2;
    bool use_b16 = (off + item_b_bytes) <= ws_size;
    if (!use_b16) item_b = nullptr;

    // 0. prep: item table + weight transposes + bias concat (one kernel)
    int itemBlocks = use_b16 ? (NITEMS*D/4)/256 : 0;
    prep_k<<<itemBlocks + 769, 256, 0, stream>>>(
        item_emb, item_b, itemBlocks,
        Wq, Wk, Wv, Wo, W1, W2,
        WqkvT, WoT, W1T, W2T,
        bq, bk, bv, bqkv);

    // 1. intra-session attention (MFMA)
    intra_k<<<ROWS/4, 256, 0, stream>>>(item_emb, item_b, sess, S, u_short);

    // 2. transformer blocks: one mega-launch per block
    for (int blk = 0; blk < 2; ++blk)
        block_k<<<BSZ, 512, 0, stream>>>(S, WqkvT, bqkv, WoT, bo,
                                         W1T, b1, W2T, b2,
                                         ln1_g, ln1_b, ln2_g, ln2_b, sess);

    // 3. fused tail: final LN + u_long + gate
    tail_k<<<BSZ, 256, 0, stream>>>(S, fn_g, fn_b, user_emb, us,
        time_emb, tdlt, u_short, gWl, gWs, gWt, gbias, Ufin);

    // 4. candidate scores
    out_k<<<(BSZ*CANDN)/32, 256, 0, stream>>>(item_emb, item_b, pred, Ufin, out);
}